// Round 1
// baseline (44.690 us; speedup 1.0000x reference)
//
#include <hip/hip_runtime.h>

#define ED 256
#define RD 128
#define NRELP 512

// ws layout (int32 words)
#define WS_COUNTS  0
#define WS_OFFSETS 512
#define WS_CURSORS 1024
#define WS_SORTED  1536
#define WS_NITEMS  (1536 + 8192)       /* 9728 */
#define WS_ITEMS   (WS_NITEMS + 2)     /* 9730 */
#define MAX_ITEMS  768
#define WS_INTS    (WS_ITEMS + 2*MAX_ITEMS)

__global__ __launch_bounds__(512) void k_zero(int* __restrict__ ws) {
    int t = threadIdx.x;
    ws[WS_COUNTS + t] = 0;
    if (t == 0) ws[WS_NITEMS] = 0;
}

__global__ __launch_bounds__(256) void k_hist(const int* __restrict__ rel,
                                              int* __restrict__ ws, int n) {
    int i = blockIdx.x * blockDim.x + threadIdx.x;
    if (i < n) atomicAdd(&ws[WS_COUNTS + rel[i]], 1);
}

// single block, 512 threads: exclusive scan of counts -> offsets/cursors,
// scan of per-relation item counts -> work-item list (rel, rowbase)
__global__ __launch_bounds__(512) void k_scan(int* __restrict__ ws) {
    __shared__ int s1[NRELP];
    __shared__ int s2[NRELP];
    int t = threadIdx.x;
    int c = ws[WS_COUNTS + t];
    s1[t] = c;
    for (int off = 1; off < NRELP; off <<= 1) {
        __syncthreads();
        int v = (t >= off) ? s1[t - off] : 0;
        __syncthreads();
        s1[t] += v;
    }
    __syncthreads();
    int excl = s1[t] - c;
    ws[WS_OFFSETS + t] = excl;
    ws[WS_CURSORS + t] = excl;

    int ic = (c + 31) >> 5;   // ceil(n/32) work items for this relation
    s2[t] = ic;
    for (int off = 1; off < NRELP; off <<= 1) {
        __syncthreads();
        int v = (t >= off) ? s2[t - off] : 0;
        __syncthreads();
        s2[t] += v;
    }
    __syncthreads();
    int iexcl = s2[t] - ic;
    if (t == NRELP - 1) ws[WS_NITEMS] = s2[t];
    for (int k = 0; k < ic; ++k) {
        ws[WS_ITEMS + 2 * (iexcl + k) + 0] = t;        // relation id
        ws[WS_ITEMS + 2 * (iexcl + k) + 1] = k << 5;   // row base within relation
    }
}

__global__ __launch_bounds__(256) void k_scatter(const int* __restrict__ rel,
                                                 int* __restrict__ ws, int n) {
    int i = blockIdx.x * blockDim.x + threadIdx.x;
    if (i < n) {
        int r = rel[i];
        int pos = atomicAdd(&ws[WS_CURSORS + r], 1);
        ws[WS_SORTED + pos] = i;
    }
}

// One block per (relation, 32-sample chunk). A = u rows (h - t) staged full-K
// in LDS; M staged in 32x128 K-chunks. 4x4 register tile per thread.
__global__ __launch_bounds__(256) void k_compute(
    const int* __restrict__ heads, const int* __restrict__ tails,
    const float* __restrict__ eemb, const float* __restrict__ remb,
    const float* __restrict__ proj, const int* __restrict__ ws,
    float* __restrict__ out)
{
    int b = blockIdx.x;
    if (b >= ws[WS_NITEMS]) return;

    const int rel     = ws[WS_ITEMS + 2 * b + 0];
    const int rowbase = ws[WS_ITEMS + 2 * b + 1];
    const int start   = ws[WS_OFFSETS + rel];
    const int n       = ws[WS_COUNTS + rel];

    __shared__ float A[32][ED + 4];   // +4 pad: float4 staging writes spread banks
    __shared__ float Ml[32][RD];

    const int tid = threadIdx.x;

    // ---- stage A: u = h - t, 32 rows x 256 ----
    {
        int row = tid >> 3;        // 0..31
        int ch  = tid & 7;         // 0..7
        int grow = rowbase + row;
        int sidx = start + min(grow, n - 1);     // clamp (writes masked later)
        int s = ws[WS_SORTED + sidx];
        const float4* hp = (const float4*)(eemb + (size_t)heads[s] * ED);
        const float4* tp = (const float4*)(eemb + (size_t)tails[s] * ED);
        #pragma unroll
        for (int j = 0; j < 8; ++j) {
            int f = 8 * j + ch;                 // 8 lanes -> 128B contiguous
            float4 hv = hp[f];
            float4 tv = tp[f];
            float4 u;
            u.x = hv.x - tv.x; u.y = hv.y - tv.y;
            u.z = hv.z - tv.z; u.w = hv.w - tv.w;
            *(float4*)&A[row][4 * f] = u;
        }
    }
    __syncthreads();

    const int c4   = tid & 31;     // column group: cols 4*c4 .. 4*c4+3
    const int rg   = tid >> 5;     // row group:    rows 4*rg .. 4*rg+3
    const int row0 = 4 * rg;
    const int nrows = n - rowbase;            // valid rows in this chunk (1..32)
    const bool active = (row0 < nrows);       // whole-wave skip when 8-row slice invalid

    float acc[4][4];
    #pragma unroll
    for (int i = 0; i < 4; ++i)
        #pragma unroll
        for (int j = 0; j < 4; ++j) acc[i][j] = 0.0f;

    const float* Mg = proj + (size_t)rel * ED * RD;

    for (int kk = 0; kk < 8; ++kk) {
        // stage M chunk [32 x 128], fully coalesced float4
        {
            const float4* src = (const float4*)(Mg + (size_t)kk * 32 * RD);
            float4* dst = (float4*)&Ml[0][0];
            #pragma unroll
            for (int jj = 0; jj < 4; ++jj)
                dst[tid + 256 * jj] = src[tid + 256 * jj];
        }
        __syncthreads();
        if (active) {
            #pragma unroll 8
            for (int d = 0; d < 32; ++d) {
                float4 m = *(const float4*)&Ml[d][4 * c4];
                int dg = (kk << 5) + d;
                float a0 = A[row0 + 0][dg];
                float a1 = A[row0 + 1][dg];
                float a2 = A[row0 + 2][dg];
                float a3 = A[row0 + 3][dg];
                acc[0][0] = fmaf(a0, m.x, acc[0][0]);
                acc[0][1] = fmaf(a0, m.y, acc[0][1]);
                acc[0][2] = fmaf(a0, m.z, acc[0][2]);
                acc[0][3] = fmaf(a0, m.w, acc[0][3]);
                acc[1][0] = fmaf(a1, m.x, acc[1][0]);
                acc[1][1] = fmaf(a1, m.y, acc[1][1]);
                acc[1][2] = fmaf(a1, m.z, acc[1][2]);
                acc[1][3] = fmaf(a1, m.w, acc[1][3]);
                acc[2][0] = fmaf(a2, m.x, acc[2][0]);
                acc[2][1] = fmaf(a2, m.y, acc[2][1]);
                acc[2][2] = fmaf(a2, m.z, acc[2][2]);
                acc[2][3] = fmaf(a2, m.w, acc[2][3]);
                acc[3][0] = fmaf(a3, m.x, acc[3][0]);
                acc[3][1] = fmaf(a3, m.y, acc[3][1]);
                acc[3][2] = fmaf(a3, m.z, acc[3][2]);
                acc[3][3] = fmaf(a3, m.w, acc[3][3]);
            }
        }
        __syncthreads();
    }

    // ---- epilogue: diff = acc + r_emb ; score = sqrt(sum over 128 cols) ----
    float4 rv = *(const float4*)(remb + (size_t)rel * RD + 4 * c4);
    #pragma unroll
    for (int i = 0; i < 4; ++i) {
        float dx = acc[i][0] + rv.x;
        float dy = acc[i][1] + rv.y;
        float dz = acc[i][2] + rv.z;
        float dw = acc[i][3] + rv.w;
        float p = dx * dx + dy * dy + dz * dz + dw * dw;
        // reduce over the 32 c4 lanes (lane bits 0..4; stays within rg half-wave)
        p += __shfl_xor(p, 1);
        p += __shfl_xor(p, 2);
        p += __shfl_xor(p, 4);
        p += __shfl_xor(p, 8);
        p += __shfl_xor(p, 16);
        int grow = rowbase + row0 + i;
        if (c4 == 0 && grow < n) {
            int s = ws[WS_SORTED + start + grow];
            out[s] = sqrtf(p);
        }
    }
}

// Fallback (only if d_ws too small): one block per sample, direct global M.
__global__ __launch_bounds__(128) void k_naive(
    const int* __restrict__ heads, const int* __restrict__ rels,
    const int* __restrict__ tails, const float* __restrict__ eemb,
    const float* __restrict__ remb, const float* __restrict__ proj,
    float* __restrict__ out)
{
    int s = blockIdx.x;
    int c = threadIdx.x;
    __shared__ float u[ED];
    __shared__ float red[128];
    int he = heads[s], te = tails[s], r = rels[s];
    const float* hp = eemb + (size_t)he * ED;
    const float* tp = eemb + (size_t)te * ED;
    u[c]       = hp[c]       - tp[c];
    u[c + 128] = hp[c + 128] - tp[c + 128];
    __syncthreads();
    const float* M = proj + (size_t)r * ED * RD;
    float acc = remb[(size_t)r * RD + c];
    for (int d = 0; d < ED; ++d) acc = fmaf(u[d], M[(size_t)d * RD + c], acc);
    red[c] = acc * acc;
    __syncthreads();
    for (int off = 64; off > 0; off >>= 1) {
        if (c < off) red[c] += red[c + off];
        __syncthreads();
    }
    if (c == 0) out[s] = sqrtf(red[0]);
}

extern "C" void kernel_launch(void* const* d_in, const int* in_sizes, int n_in,
                              void* d_out, int out_size, void* d_ws, size_t ws_size,
                              hipStream_t stream) {
    const int*   heads = (const int*)d_in[0];
    const int*   rels  = (const int*)d_in[1];
    const int*   tails = (const int*)d_in[2];
    const float* eemb  = (const float*)d_in[3];
    const float* remb  = (const float*)d_in[4];
    const float* proj  = (const float*)d_in[5];
    float* out = (float*)d_out;
    const int n = in_sizes[0];   // 8192

    if (d_ws == nullptr || ws_size < (size_t)WS_INTS * sizeof(int)) {
        k_naive<<<n, 128, 0, stream>>>(heads, rels, tails, eemb, remb, proj, out);
        return;
    }

    int* ws = (int*)d_ws;
    k_zero<<<1, 512, 0, stream>>>(ws);
    k_hist<<<(n + 255) / 256, 256, 0, stream>>>(rels, ws, n);
    k_scan<<<1, 512, 0, stream>>>(ws);
    k_scatter<<<(n + 255) / 256, 256, 0, stream>>>(rels, ws, n);
    k_compute<<<MAX_ITEMS, 256, 0, stream>>>(heads, tails, eemb, remb, proj, ws, out);
}

// Round 2
// 31.820 us; speedup vs baseline: 1.4044x; 1.4044x over previous
//
#include <hip/hip_runtime.h>
#include <hip/hip_bf16.h>

#define ED 256
#define RD 128
#define NRELP 512

// ws layout (int32 words)
#define WS_COUNTS  0
#define WS_OFFSETS 512
#define WS_SORTED  1536
#define WS_NITEMS  (1536 + 8192)       /* 9728 */
#define WS_ITEMS   (WS_NITEMS + 2)     /* 9730 */
#define MAX_ITEMS  768
#define WS_INTS    (WS_ITEMS + 2*MAX_ITEMS)

typedef float f32x4 __attribute__((ext_vector_type(4)));
typedef short s16x8 __attribute__((ext_vector_type(8)));

static __device__ __forceinline__ ushort f2bf(float f) {
    // round-to-nearest-even fp32 -> bf16 (finite inputs)
    unsigned int x = __builtin_bit_cast(unsigned int, f);
    unsigned int r = (x + 0x7fffu + ((x >> 16) & 1u)) >> 16;
    return (ushort)r;
}

// ---- fused prepass: histogram + scan + item list + counting-sort scatter ----
__global__ __launch_bounds__(1024) void k_prep(const int* __restrict__ rel,
                                               int* __restrict__ ws, int n) {
    __shared__ int cnt[NRELP];
    __shared__ int s1[NRELP];
    __shared__ int s2[NRELP];
    __shared__ int cur[NRELP];
    int t = threadIdx.x;
    if (t < NRELP) cnt[t] = 0;
    __syncthreads();

    int r[8];
    #pragma unroll
    for (int j = 0; j < 8; ++j) {
        int i = t + 1024 * j;
        r[j] = (i < n) ? rel[i] : -1;
        if (r[j] >= 0) atomicAdd(&cnt[r[j]], 1);
    }
    __syncthreads();

    int c = (t < NRELP) ? cnt[t] : 0;
    if (t < NRELP) s1[t] = c;
    for (int off = 1; off < NRELP; off <<= 1) {
        __syncthreads();
        int v = (t < NRELP && t >= off) ? s1[t - off] : 0;
        __syncthreads();
        if (t < NRELP) s1[t] += v;
    }
    __syncthreads();
    if (t < NRELP) {
        int excl = s1[t] - c;
        ws[WS_COUNTS + t]  = c;
        ws[WS_OFFSETS + t] = excl;
        cur[t] = excl;
    }

    int ic = (t < NRELP) ? (c + 31) >> 5 : 0;
    if (t < NRELP) s2[t] = ic;
    for (int off = 1; off < NRELP; off <<= 1) {
        __syncthreads();
        int v = (t < NRELP && t >= off) ? s2[t - off] : 0;
        __syncthreads();
        if (t < NRELP) s2[t] += v;
    }
    __syncthreads();
    if (t < NRELP) {
        int iexcl = s2[t] - ic;
        for (int k = 0; k < ic; ++k) {
            ws[WS_ITEMS + 2 * (iexcl + k) + 0] = t;
            ws[WS_ITEMS + 2 * (iexcl + k) + 1] = k << 5;
        }
        if (t == NRELP - 1) ws[WS_NITEMS] = s2[t];
    }
    __syncthreads();

    #pragma unroll
    for (int j = 0; j < 8; ++j) {
        if (r[j] >= 0) {
            int p = atomicAdd(&cur[r[j]], 1);
            ws[WS_SORTED + p] = t + 1024 * j;
        }
    }
}

// ---- compute: one block per (relation, 32-row chunk); bf16 MFMA ----
// 512 threads = 8 waves; wave w owns output cols [w*16, w*16+16), rows 0..31.
// A (u = h-t) staged bf16 in LDS, padded +8 ushort/row (2-way banks ~free).
// B fragments built straight from global M (fp32 -> bf16), no barriers in K-loop.
__global__ __launch_bounds__(512) void k_compute(
    const int* __restrict__ heads, const int* __restrict__ tails,
    const float* __restrict__ eemb, const float* __restrict__ remb,
    const float* __restrict__ proj, const int* __restrict__ ws,
    float* __restrict__ out)
{
    int b = blockIdx.x;
    if (b >= ws[WS_NITEMS]) return;

    const int rel     = ws[WS_ITEMS + 2 * b + 0];
    const int rowbase = ws[WS_ITEMS + 2 * b + 1];
    const int start   = ws[WS_OFFSETS + rel];
    const int n       = ws[WS_COUNTS + rel];
    const int nrows   = n - rowbase;

    __shared__ __align__(16) ushort A[32][ED + 8];
    __shared__ float red[32][8];

    const int tid = threadIdx.x;

    // stage A: u = bf16(h - t), 32 rows x 256
    {
        int row = tid >> 4;          // 0..31
        int ch  = tid & 15;          // 0..15
        int grow = rowbase + row;
        int sidx = start + min(grow, n - 1);   // clamp; masked at epilogue
        int s = ws[WS_SORTED + sidx];
        const float4* hp = (const float4*)(eemb + (size_t)heads[s] * ED);
        const float4* tp = (const float4*)(eemb + (size_t)tails[s] * ED);
        #pragma unroll
        for (int j = 0; j < 4; ++j) {
            int f = ch + 16 * j;
            float4 hv = hp[f];
            float4 tv = tp[f];
            ushort4 u;
            u.x = f2bf(hv.x - tv.x);
            u.y = f2bf(hv.y - tv.y);
            u.z = f2bf(hv.z - tv.z);
            u.w = f2bf(hv.w - tv.w);
            *(ushort4*)&A[row][4 * f] = u;
        }
    }
    __syncthreads();

    const int w    = tid >> 6;       // wave id 0..7 -> col tile base w*16
    const int lane = tid & 63;
    const int l15  = lane & 15;
    const int g    = lane >> 4;      // k-group 0..3
    const int do_rt1 = (nrows > 16);

    const float* Mg = proj + (size_t)rel * (ED * RD);

    f32x4 acc0 = {0.f, 0.f, 0.f, 0.f};
    f32x4 acc1 = {0.f, 0.f, 0.f, 0.f};

    #pragma unroll 2
    for (int k0 = 0; k0 < ED; k0 += 32) {
        // B fragment: lane holds M[k0+g*8+j][w*16+l15], j=0..7
        const float* bp = Mg + (size_t)(k0 + g * 8) * RD + w * 16 + l15;
        s16x8 fb;
        #pragma unroll
        for (int j = 0; j < 8; ++j)
            fb[j] = (short)f2bf(bp[(size_t)j * RD]);
        // A fragment: lane holds A[row][k0+g*8 .. +7]
        s16x8 fa0 = *(const s16x8*)&A[l15][k0 + g * 8];
        acc0 = __builtin_amdgcn_mfma_f32_16x16x32_bf16(fa0, fb, acc0, 0, 0, 0);
        if (do_rt1) {
            s16x8 fa1 = *(const s16x8*)&A[16 + l15][k0 + g * 8];
            acc1 = __builtin_amdgcn_mfma_f32_16x16x32_bf16(fa1, fb, acc1, 0, 0, 0);
        }
    }

    // epilogue: D row = g*4+i, col = w*16+l15; diff = D + r[col]
    float rv = remb[(size_t)rel * RD + w * 16 + l15];
    #pragma unroll
    for (int i = 0; i < 4; ++i) {
        float d0 = acc0[i] + rv;
        float p0 = d0 * d0;
        p0 += __shfl_xor(p0, 1);
        p0 += __shfl_xor(p0, 2);
        p0 += __shfl_xor(p0, 4);
        p0 += __shfl_xor(p0, 8);
        if (l15 == 0) red[g * 4 + i][w] = p0;
        if (do_rt1) {
            float d1 = acc1[i] + rv;
            float p1 = d1 * d1;
            p1 += __shfl_xor(p1, 1);
            p1 += __shfl_xor(p1, 2);
            p1 += __shfl_xor(p1, 4);
            p1 += __shfl_xor(p1, 8);
            if (l15 == 0) red[16 + g * 4 + i][w] = p1;
        }
    }
    __syncthreads();

    if (tid < 32) {
        int grow = rowbase + tid;
        if (grow < n) {
            float s = 0.f;
            #pragma unroll
            for (int q = 0; q < 8; ++q) s += red[tid][q];
            out[ws[WS_SORTED + start + grow]] = sqrtf(s);
        }
    }
}

// Fallback (only if d_ws too small): fp32, one block per sample.
__global__ __launch_bounds__(128) void k_naive(
    const int* __restrict__ heads, const int* __restrict__ rels,
    const int* __restrict__ tails, const float* __restrict__ eemb,
    const float* __restrict__ remb, const float* __restrict__ proj,
    float* __restrict__ out)
{
    int s = blockIdx.x;
    int c = threadIdx.x;
    __shared__ float u[ED];
    __shared__ float red[128];
    int he = heads[s], te = tails[s], r = rels[s];
    const float* hp = eemb + (size_t)he * ED;
    const float* tp = eemb + (size_t)te * ED;
    u[c]       = hp[c]       - tp[c];
    u[c + 128] = hp[c + 128] - tp[c + 128];
    __syncthreads();
    const float* M = proj + (size_t)r * ED * RD;
    float acc = remb[(size_t)r * RD + c];
    for (int d = 0; d < ED; ++d) acc = fmaf(u[d], M[(size_t)d * RD + c], acc);
    red[c] = acc * acc;
    __syncthreads();
    for (int off = 64; off > 0; off >>= 1) {
        if (c < off) red[c] += red[c + off];
        __syncthreads();
    }
    if (c == 0) out[s] = sqrtf(red[0]);
}

extern "C" void kernel_launch(void* const* d_in, const int* in_sizes, int n_in,
                              void* d_out, int out_size, void* d_ws, size_t ws_size,
                              hipStream_t stream) {
    const int*   heads = (const int*)d_in[0];
    const int*   rels  = (const int*)d_in[1];
    const int*   tails = (const int*)d_in[2];
    const float* eemb  = (const float*)d_in[3];
    const float* remb  = (const float*)d_in[4];
    const float* proj  = (const float*)d_in[5];
    float* out = (float*)d_out;
    const int n = in_sizes[0];   // 8192

    if (d_ws == nullptr || ws_size < (size_t)WS_INTS * sizeof(int)) {
        k_naive<<<n, 128, 0, stream>>>(heads, rels, tails, eemb, remb, proj, out);
        return;
    }

    int* ws = (int*)d_ws;
    k_prep<<<1, 1024, 0, stream>>>(rels, ws, n);
    k_compute<<<MAX_ITEMS, 512, 0, stream>>>(heads, tails, eemb, remb, proj, ws, out);
}

// Round 3
// 26.098 us; speedup vs baseline: 1.7124x; 1.2193x over previous
//
#include <hip/hip_runtime.h>

#define ED 256
#define RD 128
#define MAXC 256   // max samples per relation (B=8192, 500 rels, lambda=16.4 -> P(>256) ~ 0)

typedef float  f32x4 __attribute__((ext_vector_type(4)));
typedef short  s16x8 __attribute__((ext_vector_type(8)));
typedef unsigned int u32;
typedef unsigned int u32x4 __attribute__((ext_vector_type(4)));

// packed fp32x2 -> bf16x2 (RNE), one VALU op
static __device__ __forceinline__ u32 cvtpk(float lo, float hi) {
    u32 r;
    asm("v_cvt_pk_bf16_f32 %0, %1, %2" : "=v"(r) : "v"(lo), "v"(hi));
    return r;
}

// One block per relation. 512 threads = 8 waves; wave w owns output cols
// [16w,16w+16). Ballot-compaction of this relation's sample indices into LDS,
// then M (fp32->bf16) loaded ONCE into 32 VGPRs of B-fragments, then loop over
// 32-row chunks: A = bf16(h-t) staged in LDS (software-pipelined), 16x16x32
// bf16 MFMA, L2-norm epilogue.
__global__ __launch_bounds__(512, 4) void k_transr(
    const int* __restrict__ heads, const int* __restrict__ rels,
    const int* __restrict__ tails, const float* __restrict__ eemb,
    const float* __restrict__ remb, const float* __restrict__ proj,
    float* __restrict__ out, int n)
{
    const int r    = blockIdx.x;
    const int tid  = threadIdx.x;
    const int lane = tid & 63;
    const int w    = tid >> 6;      // wave id 0..7
    const int l15  = lane & 15;
    const int g    = lane >> 4;     // k-group 0..3

    __shared__ int idxs[MAXC];
    __shared__ int scnt;
    __shared__ __align__(16) ushort A[32][ED + 8];
    __shared__ float red[32][8];

    // ---- ballot-compaction: collect sample indices with rels[i]==r ----
    if (tid == 0) scnt = 0;
    __syncthreads();
    for (int base = 0; base < n; base += 512) {
        int i = base + tid;
        bool m = (i < n) && (rels[i] == r);
        unsigned long long mk = __ballot(m);
        int wb = 0;
        if (lane == 0) wb = atomicAdd(&scnt, __popcll(mk));
        wb = __shfl(wb, 0);
        if (m) {
            int off = wb + __popcll(mk & ((1ull << lane) - 1ull));
            if (off < MAXC) idxs[off] = i;
        }
    }
    __syncthreads();
    const int cnt = min(scnt, MAXC);
    if (cnt == 0) return;
    const int nch = (cnt + 31) >> 5;

    // ---- stage A for chunk 0 (issue entity gathers before M loads) ----
    {
        int row  = tid >> 4;          // 0..31
        int c16  = tid & 15;
        int sidx = min(row, cnt - 1); // clamp; masked at epilogue
        int s = idxs[sidx];
        const f32x4* hp = (const f32x4*)(eemb + (size_t)heads[s] * ED);
        const f32x4* tp = (const f32x4*)(eemb + (size_t)tails[s] * ED);
        #pragma unroll
        for (int j = 0; j < 4; ++j) {
            int f = c16 + 16 * j;
            f32x4 hv = hp[f], tv = tp[f];
            uint2 uu;
            uu.x = cvtpk(hv.x - tv.x, hv.y - tv.y);
            uu.y = cvtpk(hv.z - tv.z, hv.w - tv.w);
            *(uint2*)&A[row][4 * f] = uu;
        }
    }

    // ---- B fragments: lane holds bf16 M[32*s8+8g+j][16w+l15], j=0..7 ----
    const float* Mg = proj + (size_t)r * (ED * RD);
    s16x8 fb[8];
    #pragma unroll
    for (int s8 = 0; s8 < 8; ++s8) {
        const float* bp = Mg + (size_t)(32 * s8 + 8 * g) * RD + 16 * w + l15;
        float v0 = bp[0 * RD], v1 = bp[1 * RD], v2 = bp[2 * RD], v3 = bp[3 * RD];
        float v4 = bp[4 * RD], v5 = bp[5 * RD], v6 = bp[6 * RD], v7 = bp[7 * RD];
        u32x4 q;
        q.x = cvtpk(v0, v1);
        q.y = cvtpk(v2, v3);
        q.z = cvtpk(v4, v5);
        q.w = cvtpk(v6, v7);
        fb[s8] = __builtin_bit_cast(s16x8, q);
    }

    const float rv = remb[(size_t)r * RD + 16 * w + l15];

    for (int ch = 0; ch < nch; ++ch) {
        const int rowbase = ch << 5;
        const int nrows = cnt - rowbase;
        const int do1 = (nrows > 16);

        __syncthreads();   // A (this chunk) staged

        f32x4 acc0 = {0.f, 0.f, 0.f, 0.f};
        f32x4 acc1 = {0.f, 0.f, 0.f, 0.f};
        #pragma unroll
        for (int s8 = 0; s8 < 8; ++s8) {
            s16x8 fa0 = *(const s16x8*)&A[l15][(s8 << 5) + 8 * g];
            acc0 = __builtin_amdgcn_mfma_f32_16x16x32_bf16(fa0, fb[s8], acc0, 0, 0, 0);
        }
        if (do1) {
            #pragma unroll
            for (int s8 = 0; s8 < 8; ++s8) {
                s16x8 fa1 = *(const s16x8*)&A[16 + l15][(s8 << 5) + 8 * g];
                acc1 = __builtin_amdgcn_mfma_f32_16x16x32_bf16(fa1, fb[s8], acc1, 0, 0, 0);
            }
        }

        // ---- epilogue: D row = 4g+i, col = 16w+l15; diff = D + r[col] ----
        #pragma unroll
        for (int i = 0; i < 4; ++i) {
            float d0 = acc0[i] + rv;
            float p0 = d0 * d0;
            p0 += __shfl_xor(p0, 1);
            p0 += __shfl_xor(p0, 2);
            p0 += __shfl_xor(p0, 4);
            p0 += __shfl_xor(p0, 8);
            if (l15 == 0) red[4 * g + i][w] = p0;
            if (do1) {
                float d1 = acc1[i] + rv;
                float p1 = d1 * d1;
                p1 += __shfl_xor(p1, 1);
                p1 += __shfl_xor(p1, 2);
                p1 += __shfl_xor(p1, 4);
                p1 += __shfl_xor(p1, 8);
                if (l15 == 0) red[16 + 4 * g + i][w] = p1;
            }
        }
        __syncthreads();   // red ready; also A-readers (MFMA ds_reads) done

        if (tid < 32) {
            int grow = rowbase + tid;
            if (grow < cnt) {
                float s = 0.f;
                #pragma unroll
                for (int q = 0; q < 8; ++q) s += red[tid][q];
                out[idxs[grow]] = sqrtf(s);
            }
        }

        // software-pipelined A-stage for next chunk (A-readers done per barrier
        // above; out-write reads red, not A, so this overlaps safely)
        if (ch + 1 < nch) {
            int row  = tid >> 4;
            int c16  = tid & 15;
            int sidx = min(rowbase + 32 + row, cnt - 1);
            int s = idxs[sidx];
            const f32x4* hp = (const f32x4*)(eemb + (size_t)heads[s] * ED);
            const f32x4* tp = (const f32x4*)(eemb + (size_t)tails[s] * ED);
            #pragma unroll
            for (int j = 0; j < 4; ++j) {
                int f = c16 + 16 * j;
                f32x4 hv = hp[f], tv = tp[f];
                uint2 uu;
                uu.x = cvtpk(hv.x - tv.x, hv.y - tv.y);
                uu.y = cvtpk(hv.z - tv.z, hv.w - tv.w);
                *(uint2*)&A[row][4 * f] = uu;
            }
        }
    }
}

extern "C" void kernel_launch(void* const* d_in, const int* in_sizes, int n_in,
                              void* d_out, int out_size, void* d_ws, size_t ws_size,
                              hipStream_t stream) {
    const int*   heads = (const int*)d_in[0];
    const int*   rels  = (const int*)d_in[1];
    const int*   tails = (const int*)d_in[2];
    const float* eemb  = (const float*)d_in[3];
    const float* remb  = (const float*)d_in[4];
    const float* proj  = (const float*)d_in[5];
    float* out = (float*)d_out;
    const int n    = in_sizes[0];        // 8192
    const int nrel = in_sizes[4] / RD;   // 500

    k_transr<<<nrel, 512, 0, stream>>>(heads, rels, tails, eemb, remb, proj, out, n);
}

// Round 5
// 24.425 us; speedup vs baseline: 1.8296x; 1.0685x over previous
//
#include <hip/hip_runtime.h>

#define ED 256
#define RD 128
#define MAXC 256   // max samples per relation (B=8192, 500 rels, Poisson(16.4))

typedef float f32x4 __attribute__((ext_vector_type(4)));
typedef short s16x8 __attribute__((ext_vector_type(8)));
typedef unsigned int u32;
typedef unsigned int u32x4 __attribute__((ext_vector_type(4)));

// packed fp32x2 -> bf16x2 (RNE), one VALU op
static __device__ __forceinline__ u32 cvtpk(float lo, float hi) {
    u32 r;
    asm("v_cvt_pk_bf16_f32 %0, %1, %2" : "=v"(r) : "v"(lo), "v"(hi));
    return r;
}

// One block per relation. 512 threads = 8 waves; wave w owns output cols
// [16w,16w+16). Pipeline: per-match-atomic compaction scan -> lgkm-only
// barrier -> ht-index loads -> A float4 gathers -> all 64 M dword loads
// (in-flight-ordered so A conversion never waits on M) -> A->LDS bf16,
// M->VGPR bf16 fragments -> lgkm barrier -> 16x16x32 bf16 MFMA -> L2 norm.
__global__ __launch_bounds__(512, 4) void k_transr(
    const int* __restrict__ heads, const int* __restrict__ rels,
    const int* __restrict__ tails, const float* __restrict__ eemb,
    const float* __restrict__ remb, const float* __restrict__ proj,
    float* __restrict__ out, int n)
{
    const int r    = blockIdx.x;
    const int tid  = threadIdx.x;
    const int lane = tid & 63;
    const int w    = tid >> 6;      // wave id 0..7
    const int l15  = lane & 15;
    const int g    = lane >> 4;     // k-group 0..3

    __shared__ int idxs[MAXC];
    __shared__ int scnt;
    __shared__ __align__(16) ushort A[32][ED + 8];
    __shared__ float red[32][8];

    if (tid == 0) scnt = 0;
    __syncthreads();   // nothing in flight yet; free

    // ---- compaction: one LDS atomic per MATCH (~16/block total) ----
    #pragma unroll
    for (int it = 0; it < 16; ++it) {
        int i = (it << 9) + tid;
        if (i < n && rels[i] == r) {
            int p = atomicAdd(&scnt, 1);
            if (p < MAXC) idxs[p] = i;
        }
    }
    // generic tail for n > 8192 (dead for this problem)
    for (int i = (16 << 9) + tid; i < n; i += 512) {
        if (rels[i] == r) {
            int p = atomicAdd(&scnt, 1);
            if (p < MAXC) idxs[p] = i;
        }
    }
    asm volatile("s_waitcnt lgkmcnt(0)" ::: "memory");
    __builtin_amdgcn_s_barrier();        // idxs/scnt visible; no vmcnt drain

    const int cnt = min(scnt, MAXC);
    if (cnt == 0) return;
    const int nch = (cnt + 31) >> 5;

    const int row = tid >> 4;            // 0..31
    const int c16 = tid & 15;

    // ---- stage 1: ht indices + remb (oldest VMEM; retire first) ----
    int s0 = idxs[min(row, cnt - 1)];
    int hidx = heads[s0];
    int tidx = tails[s0];
    const float rvv = remb[(size_t)r * RD + 16 * w + l15];
    __builtin_amdgcn_sched_barrier(0);

    // ---- stage 2: A gathers (8 float4/lane) ----
    const f32x4* hp = (const f32x4*)(eemb + (size_t)hidx * ED);
    const f32x4* tp = (const f32x4*)(eemb + (size_t)tidx * ED);
    f32x4 ha[4], ta[4];
    #pragma unroll
    for (int j = 0; j < 4; ++j) {
        ha[j] = hp[c16 + 16 * j];
        ta[j] = tp[c16 + 16 * j];
    }
    __builtin_amdgcn_sched_barrier(0);

    // ---- stage 3: all 64 M dword loads (youngest; A conversion won't wait) ----
    const float* bbase = proj + (size_t)r * (ED * RD) + (size_t)(8 * g) * RD + 16 * w + l15;
    float mr[64];
    #pragma unroll
    for (int s8 = 0; s8 < 8; ++s8)
        #pragma unroll
        for (int j = 0; j < 8; ++j)
            mr[8 * s8 + j] = bbase[(size_t)(32 * s8 + j) * RD];
    __builtin_amdgcn_sched_barrier(0);

    // ---- A -> bf16 -> LDS (waits only on A loads) ----
    #pragma unroll
    for (int j = 0; j < 4; ++j) {
        uint2 uu;
        uu.x = cvtpk(ha[j].x - ta[j].x, ha[j].y - ta[j].y);
        uu.y = cvtpk(ha[j].z - ta[j].z, ha[j].w - ta[j].w);
        *(uint2*)&A[row][4 * (c16 + 16 * j)] = uu;
    }

    // ---- M -> bf16 B-fragments in VGPRs ----
    s16x8 fb[8];
    #pragma unroll
    for (int s8 = 0; s8 < 8; ++s8) {
        u32x4 q;
        q.x = cvtpk(mr[8 * s8 + 0], mr[8 * s8 + 1]);
        q.y = cvtpk(mr[8 * s8 + 2], mr[8 * s8 + 3]);
        q.z = cvtpk(mr[8 * s8 + 4], mr[8 * s8 + 5]);
        q.w = cvtpk(mr[8 * s8 + 6], mr[8 * s8 + 7]);
        fb[s8] = __builtin_bit_cast(s16x8, q);
    }

    for (int ch = 0; ch < nch; ++ch) {
        if (ch > 0) {
            // rare path (cnt > 32): stage this chunk's A
            int s = idxs[min((ch << 5) + row, cnt - 1)];
            const f32x4* hp2 = (const f32x4*)(eemb + (size_t)heads[s] * ED);
            const f32x4* tp2 = (const f32x4*)(eemb + (size_t)tails[s] * ED);
            #pragma unroll
            for (int j = 0; j < 4; ++j) {
                f32x4 hv = hp2[c16 + 16 * j], tv = tp2[c16 + 16 * j];
                uint2 uu;
                uu.x = cvtpk(hv.x - tv.x, hv.y - tv.y);
                uu.y = cvtpk(hv.z - tv.z, hv.w - tv.w);
                *(uint2*)&A[row][4 * (c16 + 16 * j)] = uu;
            }
        }
        asm volatile("s_waitcnt lgkmcnt(0)" ::: "memory");
        __builtin_amdgcn_s_barrier();    // A staged; M loads may still be in flight

        const int rowbase = ch << 5;
        const int do1 = (cnt - rowbase) > 16;

        f32x4 acc0 = {0.f, 0.f, 0.f, 0.f};
        f32x4 acc1 = {0.f, 0.f, 0.f, 0.f};
        #pragma unroll
        for (int s8 = 0; s8 < 8; ++s8) {
            s16x8 fa0 = *(const s16x8*)&A[l15][(s8 << 5) + 8 * g];
            acc0 = __builtin_amdgcn_mfma_f32_16x16x32_bf16(fa0, fb[s8], acc0, 0, 0, 0);
        }
        if (do1) {
            #pragma unroll
            for (int s8 = 0; s8 < 8; ++s8) {
                s16x8 fa1 = *(const s16x8*)&A[16 + l15][(s8 << 5) + 8 * g];
                acc1 = __builtin_amdgcn_mfma_f32_16x16x32_bf16(fa1, fb[s8], acc1, 0, 0, 0);
            }
        }

        // ---- epilogue: D row = 4g+i, col = 16w+l15; diff = D + r[col] ----
        #pragma unroll
        for (int i = 0; i < 4; ++i) {
            float d0 = acc0[i] + rvv;
            float p0 = d0 * d0;
            p0 += __shfl_xor(p0, 1);
            p0 += __shfl_xor(p0, 2);
            p0 += __shfl_xor(p0, 4);
            p0 += __shfl_xor(p0, 8);
            if (l15 == 0) red[4 * g + i][w] = p0;
            if (do1) {
                float d1 = acc1[i] + rvv;
                float p1 = d1 * d1;
                p1 += __shfl_xor(p1, 1);
                p1 += __shfl_xor(p1, 2);
                p1 += __shfl_xor(p1, 4);
                p1 += __shfl_xor(p1, 8);
                if (l15 == 0) red[16 + 4 * g + i][w] = p1;
            }
        }
        __syncthreads();   // red ready; A readers done before next-chunk overwrite

        if (tid < 32) {
            int grow = rowbase + tid;
            if (grow < cnt) {
                float s = 0.f;
                #pragma unroll
                for (int q = 0; q < 8; ++q) s += red[tid][q];
                out[idxs[grow]] = sqrtf(s);
            }
        }
    }
}

extern "C" void kernel_launch(void* const* d_in, const int* in_sizes, int n_in,
                              void* d_out, int out_size, void* d_ws, size_t ws_size,
                              hipStream_t stream) {
    const int*   heads = (const int*)d_in[0];
    const int*   rels  = (const int*)d_in[1];
    const int*   tails = (const int*)d_in[2];
    const float* eemb  = (const float*)d_in[3];
    const float* remb  = (const float*)d_in[4];
    const float* proj  = (const float*)d_in[5];
    float* out = (float*)d_out;
    const int n    = in_sizes[0];        // 8192
    const int nrel = in_sizes[4] / RD;   // 500

    k_transr<<<nrel, 512, 0, stream>>>(heads, rels, tails, eemb, remb, proj, out, n);
}

// Round 6
// 20.685 us; speedup vs baseline: 2.1605x; 1.1808x over previous
//
#include <hip/hip_runtime.h>

#define ED 256
#define RD 128
#define MAXC 256   // max samples per relation (B=8192, 500 rels, Poisson(16.4))

typedef float f32x4 __attribute__((ext_vector_type(4)));
typedef short s16x8 __attribute__((ext_vector_type(8)));
typedef int   i32x4 __attribute__((ext_vector_type(4)));
typedef unsigned int u32;
typedef unsigned int u32x4 __attribute__((ext_vector_type(4)));

// packed fp32x2 -> bf16x2 (RNE), one VALU op
static __device__ __forceinline__ u32 cvtpk(float lo, float hi) {
    u32 r;
    asm("v_cvt_pk_bf16_f32 %0, %1, %2" : "=v"(r) : "v"(lo), "v"(hi));
    return r;
}

// One block per relation. 512 threads = 8 waves; wave w owns output cols
// [16w,16w+16). Issue order (in-order vmcnt retirement is the design axis):
//   [oldest] rels scan (4x int4)  -> M 64 dwords -> [after compaction barrier]
//   A float4 gathers [youngest].
// Compaction's wait covers only the scan loads; the 128KB M stream is already
// in flight while the block compacts. A-gathers masked to row < cnt.
__global__ __launch_bounds__(512, 4) void k_transr(
    const int* __restrict__ heads, const int* __restrict__ rels,
    const int* __restrict__ tails, const float* __restrict__ eemb,
    const float* __restrict__ remb, const float* __restrict__ proj,
    float* __restrict__ out, int n)
{
    const int r    = blockIdx.x;
    const int tid  = threadIdx.x;
    const int lane = tid & 63;
    const int w    = tid >> 6;      // wave id 0..7
    const int l15  = lane & 15;
    const int g    = lane >> 4;     // k-group 0..3

    __shared__ int idxs[MAXC];
    __shared__ int scnt;
    __shared__ __align__(16) ushort A[32][ED + 8];
    __shared__ float red[32][8];

    if (tid == 0) scnt = 0;
    __syncthreads();   // nothing in flight yet; free

    // ---- phase 1 (oldest VMEM): rels scan, 4x int4 per thread ----
    const i32x4* rels4 = (const i32x4*)rels;
    const int nv4 = n >> 2;
    i32x4 rv4[4];
    #pragma unroll
    for (int it = 0; it < 4; ++it) {
        int i = tid + 512 * it;
        if (i < nv4) rv4[it] = rels4[i];
        else         rv4[it] = (i32x4){-1, -1, -1, -1};
    }
    __builtin_amdgcn_sched_barrier(0);

    // ---- phase 2: remb + all 64 M dword loads (stream in flight early) ----
    const float rvv = remb[(size_t)r * RD + 16 * w + l15];
    const float* bbase = proj + (size_t)r * (ED * RD) + (size_t)(8 * g) * RD + 16 * w + l15;
    float mr[64];
    #pragma unroll
    for (int s8 = 0; s8 < 8; ++s8)
        #pragma unroll
        for (int j = 0; j < 8; ++j)
            mr[8 * s8 + j] = bbase[(size_t)(32 * s8 + j) * RD];
    __builtin_amdgcn_sched_barrier(0);

    // ---- phase 3: compaction (waits only the oldest scan loads) ----
    #pragma unroll
    for (int it = 0; it < 4; ++it) {
        #pragma unroll
        for (int c = 0; c < 4; ++c) {
            if (rv4[it][c] == r) {
                int p = atomicAdd(&scnt, 1);
                if (p < MAXC) idxs[p] = 4 * (tid + 512 * it) + c;
            }
        }
    }
    if (n > 8192) {   // generic tail (dead for this problem)
        for (int i = min(nv4 << 2, 8192) + tid; i < n; i += 512) {
            if (rels[i] == r) {
                int p = atomicAdd(&scnt, 1);
                if (p < MAXC) idxs[p] = i;
            }
        }
    }
    asm volatile("s_waitcnt lgkmcnt(0)" ::: "memory");
    __builtin_amdgcn_s_barrier();        // idxs/scnt visible; M stays in flight

    const int cnt = min(scnt, MAXC);
    if (cnt == 0) return;
    const int nch = (cnt + 31) >> 5;

    const int row = tid >> 4;            // 0..31
    const int c16 = tid & 15;
    const bool arow = (row < cnt);

    // ---- phase 4 (youngest): A gathers for chunk 0, masked ----
    f32x4 ha[4], ta[4];
    if (arow) {
        int s0 = idxs[row];
        const f32x4* hp = (const f32x4*)(eemb + (size_t)heads[s0] * ED);
        const f32x4* tp = (const f32x4*)(eemb + (size_t)tails[s0] * ED);
        #pragma unroll
        for (int j = 0; j < 4; ++j) {
            ha[j] = hp[c16 + 16 * j];
            ta[j] = tp[c16 + 16 * j];
        }
    }
    __builtin_amdgcn_sched_barrier(0);

    // ---- phase 5: M -> bf16 B-fragments (M is oldest in flight: cheap wait) ----
    s16x8 fb[8];
    #pragma unroll
    for (int s8 = 0; s8 < 8; ++s8) {
        u32x4 q;
        q.x = cvtpk(mr[8 * s8 + 0], mr[8 * s8 + 1]);
        q.y = cvtpk(mr[8 * s8 + 2], mr[8 * s8 + 3]);
        q.z = cvtpk(mr[8 * s8 + 4], mr[8 * s8 + 5]);
        q.w = cvtpk(mr[8 * s8 + 6], mr[8 * s8 + 7]);
        fb[s8] = __builtin_bit_cast(s16x8, q);
    }

    // ---- phase 6: A -> bf16 -> LDS (masked) ----
    if (arow) {
        #pragma unroll
        for (int j = 0; j < 4; ++j) {
            uint2 uu;
            uu.x = cvtpk(ha[j].x - ta[j].x, ha[j].y - ta[j].y);
            uu.y = cvtpk(ha[j].z - ta[j].z, ha[j].w - ta[j].w);
            *(uint2*)&A[row][4 * (c16 + 16 * j)] = uu;
        }
    }

    for (int ch = 0; ch < nch; ++ch) {
        if (ch > 0) {
            // rare path (cnt > 32): stage this chunk's A, masked
            int grow = (ch << 5) + row;
            if (grow < cnt) {
                int s = idxs[grow];
                const f32x4* hp2 = (const f32x4*)(eemb + (size_t)heads[s] * ED);
                const f32x4* tp2 = (const f32x4*)(eemb + (size_t)tails[s] * ED);
                #pragma unroll
                for (int j = 0; j < 4; ++j) {
                    f32x4 hv = hp2[c16 + 16 * j], tv = tp2[c16 + 16 * j];
                    uint2 uu;
                    uu.x = cvtpk(hv.x - tv.x, hv.y - tv.y);
                    uu.y = cvtpk(hv.z - tv.z, hv.w - tv.w);
                    *(uint2*)&A[row][4 * (c16 + 16 * j)] = uu;
                }
            }
        }
        asm volatile("s_waitcnt lgkmcnt(0)" ::: "memory");
        __builtin_amdgcn_s_barrier();    // A staged (ds_writes drained per-wave)

        const int rowbase = ch << 5;
        const int do1 = (cnt - rowbase) > 16;

        f32x4 acc0 = {0.f, 0.f, 0.f, 0.f};
        f32x4 acc1 = {0.f, 0.f, 0.f, 0.f};
        #pragma unroll
        for (int s8 = 0; s8 < 8; ++s8) {
            s16x8 fa0 = *(const s16x8*)&A[l15][(s8 << 5) + 8 * g];
            acc0 = __builtin_amdgcn_mfma_f32_16x16x32_bf16(fa0, fb[s8], acc0, 0, 0, 0);
        }
        if (do1) {
            #pragma unroll
            for (int s8 = 0; s8 < 8; ++s8) {
                s16x8 fa1 = *(const s16x8*)&A[16 + l15][(s8 << 5) + 8 * g];
                acc1 = __builtin_amdgcn_mfma_f32_16x16x32_bf16(fa1, fb[s8], acc1, 0, 0, 0);
            }
        }

        // ---- epilogue: D row = 4g+i, col = 16w+l15; diff = D + r[col] ----
        #pragma unroll
        for (int i = 0; i < 4; ++i) {
            float d0 = acc0[i] + rvv;
            float p0 = d0 * d0;
            p0 += __shfl_xor(p0, 1);
            p0 += __shfl_xor(p0, 2);
            p0 += __shfl_xor(p0, 4);
            p0 += __shfl_xor(p0, 8);
            if (l15 == 0) red[4 * g + i][w] = p0;
            if (do1) {
                float d1 = acc1[i] + rvv;
                float p1 = d1 * d1;
                p1 += __shfl_xor(p1, 1);
                p1 += __shfl_xor(p1, 2);
                p1 += __shfl_xor(p1, 4);
                p1 += __shfl_xor(p1, 8);
                if (l15 == 0) red[16 + 4 * g + i][w] = p1;
            }
        }
        __syncthreads();   // red ready; A readers done before next-chunk overwrite

        if (tid < 32) {
            int grow = rowbase + tid;
            if (grow < cnt) {
                float s = 0.f;
                #pragma unroll
                for (int q = 0; q < 8; ++q) s += red[tid][q];
                out[idxs[grow]] = sqrtf(s);
            }
        }
    }
}

extern "C" void kernel_launch(void* const* d_in, const int* in_sizes, int n_in,
                              void* d_out, int out_size, void* d_ws, size_t ws_size,
                              hipStream_t stream) {
    const int*   heads = (const int*)d_in[0];
    const int*   rels  = (const int*)d_in[1];
    const int*   tails = (const int*)d_in[2];
    const float* eemb  = (const float*)d_in[3];
    const float* remb  = (const float*)d_in[4];
    const float* proj  = (const float*)d_in[5];
    float* out = (float*)d_out;
    const int n    = in_sizes[0];        // 8192
    const int nrel = in_sizes[4] / RD;   // 500

    k_transr<<<nrel, 512, 0, stream>>>(heads, rels, tails, eemb, remb, proj, out, n);
}

// Round 7
// 20.133 us; speedup vs baseline: 2.2197x; 1.0274x over previous
//
#include <hip/hip_runtime.h>

#define ED 256
#define RD 128
#define MAXC 256   // max samples per relation (B=8192, 500 rels, Poisson(16.4))

typedef float f32x4 __attribute__((ext_vector_type(4)));
typedef short s16x8 __attribute__((ext_vector_type(8)));
typedef int   i32x4 __attribute__((ext_vector_type(4)));
typedef unsigned int u32;
typedef unsigned int u32x4 __attribute__((ext_vector_type(4)));

// packed fp32x2 -> bf16x2 (RNE), one VALU op
static __device__ __forceinline__ u32 cvtpk(float lo, float hi) {
    u32 r;
    asm("v_cvt_pk_bf16_f32 %0, %1, %2" : "=v"(r) : "v"(lo), "v"(hi));
    return r;
}

#define SBAR() __builtin_amdgcn_sched_barrier(0)

// One block per relation; 512 threads = 8 waves; wave w owns output cols
// [16w,16w+16). M staged through a 2-deep rotating register pipeline
// (16-dword groups) so peak VGPR ~95 (no spill at the 128 cap), while the
// VMEM stream stays deep. In-order vmcnt: each convert waits only its group.
__global__ __launch_bounds__(512, 4) void k_transr(
    const int* __restrict__ heads, const int* __restrict__ rels,
    const int* __restrict__ tails, const float* __restrict__ eemb,
    const float* __restrict__ remb, const float* __restrict__ proj,
    float* __restrict__ out, int n)
{
    const int r    = blockIdx.x;
    const int tid  = threadIdx.x;
    const int lane = tid & 63;
    const int w    = tid >> 6;      // wave id 0..7
    const int l15  = lane & 15;
    const int g    = lane >> 4;     // k-group 0..3

    __shared__ int idxs[MAXC];
    __shared__ int scnt;
    __shared__ __align__(16) ushort A[32][ED + 8];
    __shared__ float red[32][8];

    if (tid == 0) scnt = 0;
    __syncthreads();   // nothing in flight yet; free

    // ---- phase 1 (oldest VMEM): rels scan, 4x int4 per thread ----
    const i32x4* rels4 = (const i32x4*)rels;
    const int nv4 = n >> 2;
    i32x4 rv4[4];
    #pragma unroll
    for (int it = 0; it < 4; ++it) {
        int i = tid + 512 * it;
        if (i < nv4) rv4[it] = rels4[i];
        else         rv4[it] = (i32x4){-1, -1, -1, -1};
    }
    SBAR();

    // ---- phase 2: M groups 0,1 (s8 = 0..3), 32 dwords in flight ----
    const float* bbase = proj + (size_t)r * (ED * RD) + (size_t)(8 * g) * RD + 16 * w + l15;
    float mA[16], mB[16];
    #pragma unroll
    for (int s8 = 0; s8 < 2; ++s8)
        #pragma unroll
        for (int j = 0; j < 8; ++j)
            mA[8 * s8 + j] = bbase[(size_t)(32 * s8 + j) * RD];
    SBAR();
    #pragma unroll
    for (int s8 = 2; s8 < 4; ++s8)
        #pragma unroll
        for (int j = 0; j < 8; ++j)
            mB[8 * (s8 - 2) + j] = bbase[(size_t)(32 * s8 + j) * RD];
    SBAR();

    // ---- phase 3: compaction (waits only the oldest rels loads) ----
    #pragma unroll
    for (int it = 0; it < 4; ++it) {
        #pragma unroll
        for (int c = 0; c < 4; ++c) {
            if (rv4[it][c] == r) {
                int p = atomicAdd(&scnt, 1);
                if (p < MAXC) idxs[p] = 4 * (tid + 512 * it) + c;
            }
        }
    }
    if (n > 8192) {   // generic tail (dead for this problem)
        for (int i = min(nv4 << 2, 8192) + tid; i < n; i += 512) {
            if (rels[i] == r) {
                int p = atomicAdd(&scnt, 1);
                if (p < MAXC) idxs[p] = i;
            }
        }
    }
    asm volatile("s_waitcnt lgkmcnt(0)" ::: "memory");
    __builtin_amdgcn_s_barrier();        // idxs/scnt visible; M stays in flight

    const int cnt = min(scnt, MAXC);
    if (cnt == 0) return;
    const int nch = (cnt + 31) >> 5;

    const int row = tid >> 4;            // 0..31
    const int c16 = tid & 15;
    const bool arow = (row < cnt);

    // ---- phase 4: A gathers + remb ----
    f32x4 ha[4], ta[4];
    if (arow) {
        int s0 = idxs[row];
        const f32x4* hp = (const f32x4*)(eemb + (size_t)heads[s0] * ED);
        const f32x4* tp = (const f32x4*)(eemb + (size_t)tails[s0] * ED);
        #pragma unroll
        for (int j = 0; j < 4; ++j) {
            ha[j] = hp[c16 + 16 * j];
            ta[j] = tp[c16 + 16 * j];
        }
    }
    const float rvv = remb[(size_t)r * RD + 16 * w + l15];
    SBAR();

    s16x8 fb[8];
    u32x4 q;

    // ---- convert M g0 (mA s8=0,1) -> fb[0,1]; then reload mA with g2 ----
    #pragma unroll
    for (int s8 = 0; s8 < 2; ++s8) {
        q.x = cvtpk(mA[8 * s8 + 0], mA[8 * s8 + 1]);
        q.y = cvtpk(mA[8 * s8 + 2], mA[8 * s8 + 3]);
        q.z = cvtpk(mA[8 * s8 + 4], mA[8 * s8 + 5]);
        q.w = cvtpk(mA[8 * s8 + 6], mA[8 * s8 + 7]);
        fb[s8] = __builtin_bit_cast(s16x8, q);
    }
    SBAR();
    #pragma unroll
    for (int s8 = 4; s8 < 6; ++s8)
        #pragma unroll
        for (int j = 0; j < 8; ++j)
            mA[8 * (s8 - 4) + j] = bbase[(size_t)(32 * s8 + j) * RD];
    SBAR();

    // ---- convert M g1 (mB s8=2,3) -> fb[2,3]; then reload mB with g3 ----
    #pragma unroll
    for (int s8 = 0; s8 < 2; ++s8) {
        q.x = cvtpk(mB[8 * s8 + 0], mB[8 * s8 + 1]);
        q.y = cvtpk(mB[8 * s8 + 2], mB[8 * s8 + 3]);
        q.z = cvtpk(mB[8 * s8 + 4], mB[8 * s8 + 5]);
        q.w = cvtpk(mB[8 * s8 + 6], mB[8 * s8 + 7]);
        fb[2 + s8] = __builtin_bit_cast(s16x8, q);
    }
    SBAR();
    #pragma unroll
    for (int s8 = 6; s8 < 8; ++s8)
        #pragma unroll
        for (int j = 0; j < 8; ++j)
            mB[8 * (s8 - 6) + j] = bbase[(size_t)(32 * s8 + j) * RD];
    SBAR();

    // ---- A -> bf16 -> LDS (A is oldest in flight; wait leaves M g2,g3 out) ----
    if (arow) {
        #pragma unroll
        for (int j = 0; j < 4; ++j) {
            uint2 uu;
            uu.x = cvtpk(ha[j].x - ta[j].x, ha[j].y - ta[j].y);
            uu.y = cvtpk(ha[j].z - ta[j].z, ha[j].w - ta[j].w);
            *(uint2*)&A[row][4 * (c16 + 16 * j)] = uu;
        }
    }
    SBAR();

    // ---- convert M g2 -> fb[4,5]; M g3 -> fb[6,7] ----
    #pragma unroll
    for (int s8 = 0; s8 < 2; ++s8) {
        q.x = cvtpk(mA[8 * s8 + 0], mA[8 * s8 + 1]);
        q.y = cvtpk(mA[8 * s8 + 2], mA[8 * s8 + 3]);
        q.z = cvtpk(mA[8 * s8 + 4], mA[8 * s8 + 5]);
        q.w = cvtpk(mA[8 * s8 + 6], mA[8 * s8 + 7]);
        fb[4 + s8] = __builtin_bit_cast(s16x8, q);
    }
    #pragma unroll
    for (int s8 = 0; s8 < 2; ++s8) {
        q.x = cvtpk(mB[8 * s8 + 0], mB[8 * s8 + 1]);
        q.y = cvtpk(mB[8 * s8 + 2], mB[8 * s8 + 3]);
        q.z = cvtpk(mB[8 * s8 + 4], mB[8 * s8 + 5]);
        q.w = cvtpk(mB[8 * s8 + 6], mB[8 * s8 + 7]);
        fb[6 + s8] = __builtin_bit_cast(s16x8, q);
    }

    for (int ch = 0; ch < nch; ++ch) {
        if (ch > 0) {
            // rare path (cnt > 32): stage this chunk's A, masked
            int grow = (ch << 5) + row;
            if (grow < cnt) {
                int s = idxs[grow];
                const f32x4* hp2 = (const f32x4*)(eemb + (size_t)heads[s] * ED);
                const f32x4* tp2 = (const f32x4*)(eemb + (size_t)tails[s] * ED);
                #pragma unroll
                for (int j = 0; j < 4; ++j) {
                    f32x4 hv = hp2[c16 + 16 * j], tv = tp2[c16 + 16 * j];
                    uint2 uu;
                    uu.x = cvtpk(hv.x - tv.x, hv.y - tv.y);
                    uu.y = cvtpk(hv.z - tv.z, hv.w - tv.w);
                    *(uint2*)&A[row][4 * (c16 + 16 * j)] = uu;
                }
            }
        }
        asm volatile("s_waitcnt lgkmcnt(0)" ::: "memory");
        __builtin_amdgcn_s_barrier();    // A staged (ds_writes drained per-wave)

        const int rowbase = ch << 5;
        const int do1 = (cnt - rowbase) > 16;

        f32x4 acc0 = {0.f, 0.f, 0.f, 0.f};
        f32x4 acc1 = {0.f, 0.f, 0.f, 0.f};
        #pragma unroll
        for (int s8 = 0; s8 < 8; ++s8) {
            s16x8 fa0 = *(const s16x8*)&A[l15][(s8 << 5) + 8 * g];
            acc0 = __builtin_amdgcn_mfma_f32_16x16x32_bf16(fa0, fb[s8], acc0, 0, 0, 0);
        }
        if (do1) {
            #pragma unroll
            for (int s8 = 0; s8 < 8; ++s8) {
                s16x8 fa1 = *(const s16x8*)&A[16 + l15][(s8 << 5) + 8 * g];
                acc1 = __builtin_amdgcn_mfma_f32_16x16x32_bf16(fa1, fb[s8], acc1, 0, 0, 0);
            }
        }

        // ---- epilogue: D row = 4g+i, col = 16w+l15; diff = D + r[col] ----
        #pragma unroll
        for (int i = 0; i < 4; ++i) {
            float d0 = acc0[i] + rvv;
            float p0 = d0 * d0;
            p0 += __shfl_xor(p0, 1);
            p0 += __shfl_xor(p0, 2);
            p0 += __shfl_xor(p0, 4);
            p0 += __shfl_xor(p0, 8);
            if (l15 == 0) red[4 * g + i][w] = p0;
            if (do1) {
                float d1 = acc1[i] + rvv;
                float p1 = d1 * d1;
                p1 += __shfl_xor(p1, 1);
                p1 += __shfl_xor(p1, 2);
                p1 += __shfl_xor(p1, 4);
                p1 += __shfl_xor(p1, 8);
                if (l15 == 0) red[16 + 4 * g + i][w] = p1;
            }
        }
        __syncthreads();   // red ready; A readers done before next-chunk overwrite

        if (tid < 32) {
            int grow = rowbase + tid;
            if (grow < cnt) {
                float s = 0.f;
                #pragma unroll
                for (int q2 = 0; q2 < 8; ++q2) s += red[tid][q2];
                out[idxs[grow]] = sqrtf(s);
            }
        }
    }
}

extern "C" void kernel_launch(void* const* d_in, const int* in_sizes, int n_in,
                              void* d_out, int out_size, void* d_ws, size_t ws_size,
                              hipStream_t stream) {
    const int*   heads = (const int*)d_in[0];
    const int*   rels  = (const int*)d_in[1];
    const int*   tails = (const int*)d_in[2];
    const float* eemb  = (const float*)d_in[3];
    const float* remb  = (const float*)d_in[4];
    const float* proj  = (const float*)d_in[5];
    float* out = (float*)d_out;
    const int n    = in_sizes[0];        // 8192
    const int nrel = in_sizes[4] / RD;   // 500

    k_transr<<<nrel, 512, 0, stream>>>(heads, rels, tails, eemb, remb, proj, out, n);
}